// Round 1
// baseline (1277.587 us; speedup 1.0000x reference)
//
#include <hip/hip_runtime.h>
#include <math.h>

#define N_NODES 100000
#define N_FEAT  512
#define HIDDEN  128
#define N_CLASS 16
#define N_EDGES 3200000
#define ALPHA   0.25f

constexpr int BM = 64;   // node rows per block
constexpr int BK = 16;   // K tile

// ---------------------------------------------------------------------------
// Fused MLP: local_logits = relu(x @ W1) @ W2
// Block: 256 threads, 64 rows x 128 hidden tile. W2 + h-tile staged in LDS.
// ---------------------------------------------------------------------------
__global__ __launch_bounds__(256) void fused_mlp(const float* __restrict__ x,
                                                 const float* __restrict__ W1,
                                                 const float* __restrict__ W2,
                                                 float* __restrict__ local_out) {
    __shared__ float As[BM][BK];            // 4 KB
    __shared__ float Bs[BK][HIDDEN];        // 8 KB
    __shared__ float W2s[HIDDEN * N_CLASS]; // 8 KB
    __shared__ float Hs[BM][HIDDEN + 4];    // 33 KB, pad 4 -> 2-way-max bank alias

    const int tid = threadIdx.x;
    const int block_row = blockIdx.x * BM;

    // stage W2 (128x16 = 512 float4)
    for (int i = tid; i < HIDDEN * N_CLASS / 4; i += 256)
        ((float4*)W2s)[i] = ((const float4*)W2)[i];

    const int tx = tid & 31;   // 32 col-groups of 4
    const int ty = tid >> 5;   // 8 row-groups of 8

    float4 acc[8];
#pragma unroll
    for (int r = 0; r < 8; ++r) acc[r] = make_float4(0.f, 0.f, 0.f, 0.f);

    // A-tile load map: thread t -> row t/4, 4-float k-chunk t%4
    const int a_row  = tid >> 2;
    const int a_k4   = (tid & 3) * 4;
    const int a_grow = block_row + a_row;
    const bool a_valid = a_grow < N_NODES;

    for (int k0 = 0; k0 < N_FEAT; k0 += BK) {
        float4 av = make_float4(0.f, 0.f, 0.f, 0.f);
        if (a_valid)
            av = *(const float4*)&x[(size_t)a_grow * N_FEAT + k0 + a_k4];
        *(float4*)&As[a_row][a_k4] = av;

#pragma unroll
        for (int l = 0; l < 2; ++l) {             // B tile: 512 float4, 2/thread
            int idx  = tid + l * 256;
            int brow = idx >> 5, bcol = (idx & 31) * 4;
            *(float4*)&Bs[brow][bcol] =
                *(const float4*)&W1[(size_t)(k0 + brow) * HIDDEN + bcol];
        }
        __syncthreads();

#pragma unroll
        for (int kc = 0; kc < 4; ++kc) {
            float4 a4[8];
#pragma unroll
            for (int r = 0; r < 8; ++r)
                a4[r] = *(float4*)&As[ty * 8 + r][kc * 4];
#pragma unroll
            for (int j = 0; j < 4; ++j) {
                float4 b = *(float4*)&Bs[kc * 4 + j][tx * 4];
#pragma unroll
                for (int r = 0; r < 8; ++r) {
                    float a = (j == 0) ? a4[r].x : (j == 1) ? a4[r].y
                              : (j == 2) ? a4[r].z : a4[r].w;
                    acc[r].x += a * b.x; acc[r].y += a * b.y;
                    acc[r].z += a * b.z; acc[r].w += a * b.w;
                }
            }
        }
        __syncthreads();
    }

    // relu -> Hs
#pragma unroll
    for (int r = 0; r < 8; ++r) {
        float4 v = acc[r];
        v.x = fmaxf(v.x, 0.f); v.y = fmaxf(v.y, 0.f);
        v.z = fmaxf(v.z, 0.f); v.w = fmaxf(v.w, 0.f);
        *(float4*)&Hs[ty * 8 + r][tx * 4] = v;
    }
    __syncthreads();

    // GEMM2: thread -> row tid/4, col-chunk (tid%4)*4
    const int row = tid >> 2;
    const int c4  = (tid & 3) * 4;
    float4 o = make_float4(0.f, 0.f, 0.f, 0.f);
#pragma unroll 8
    for (int k = 0; k < HIDDEN; ++k) {
        float  h = Hs[row][k];
        float4 w = *(float4*)&W2s[k * N_CLASS + c4];
        o.x += h * w.x; o.y += h * w.y; o.z += h * w.z; o.w += h * w.w;
    }
    int grow = block_row + row;
    if (grow < N_NODES)
        *(float4*)&local_out[(size_t)grow * N_CLASS + c4] = o;
}

// ---------------------------------------------------------------------------
// CSR build: degree histogram -> single-block scan -> scatter
// ---------------------------------------------------------------------------
__global__ void hist_kernel(const int* __restrict__ src, int* __restrict__ deg) {
    int e = blockIdx.x * blockDim.x + threadIdx.x;
    if (e < N_EDGES) atomicAdd(&deg[src[e]], 1);
}

__global__ __launch_bounds__(1024) void scan_kernel(const int* __restrict__ deg,
                                                    int* __restrict__ row_ptr,
                                                    int* __restrict__ cursor,
                                                    float* __restrict__ scale) {
    __shared__ int sums[1024];
    const int tid = threadIdx.x;
    const int chunk = (N_NODES + 1023) / 1024;   // 98
    int start = tid * chunk;
    int end   = start + chunk; if (end > N_NODES) end = N_NODES;
    if (start > N_NODES) start = N_NODES;

    int s = 0;
    for (int i = start; i < end; ++i) s += deg[i];
    sums[tid] = s;
    __syncthreads();

    // Hillis-Steele inclusive scan
    for (int off = 1; off < 1024; off <<= 1) {
        int t = (tid >= off) ? sums[tid - off] : 0;
        __syncthreads();
        sums[tid] += t;
        __syncthreads();
    }

    int run = sums[tid] - s;  // exclusive prefix for this chunk
    for (int i = start; i < end; ++i) {
        row_ptr[i] = run;
        cursor[i]  = run;
        int d = deg[i];
        scale[i] = (1.0f - ALPHA) / fmaxf((float)d, 1e-12f);
        run += d;
    }
    if (tid == 1023) row_ptr[N_NODES] = sums[1023];
}

__global__ void scatter_kernel(const int* __restrict__ src,
                               const int* __restrict__ dst,
                               int* __restrict__ cursor,
                               int* __restrict__ col) {
    int e = blockIdx.x * blockDim.x + threadIdx.x;
    if (e < N_EDGES) {
        int pos = atomicAdd(&cursor[src[e]], 1);
        col[pos] = dst[e];
    }
}

// ---------------------------------------------------------------------------
// SpMM + axpby: Lout[i] = scale[i] * sum_{j in N(i)} Lin[j] + ALPHA*local[i]
// ---------------------------------------------------------------------------
__global__ void spmm_kernel(const int* __restrict__ row_ptr,
                            const int* __restrict__ col,
                            const float* __restrict__ scale,
                            const float* __restrict__ Lin,
                            const float* __restrict__ local,
                            float* __restrict__ Lout) {
    int i = blockIdx.x * blockDim.x + threadIdx.x;
    if (i >= N_NODES) return;
    int s = row_ptr[i], e = row_ptr[i + 1];
    float4 a0 = make_float4(0.f,0.f,0.f,0.f), a1 = a0, a2 = a0, a3 = a0;
    for (int idx = s; idx < e; ++idx) {
        const float4* Lr = (const float4*)(Lin + (size_t)col[idx] * N_CLASS);
        float4 v0 = Lr[0], v1 = Lr[1], v2 = Lr[2], v3 = Lr[3];
        a0.x += v0.x; a0.y += v0.y; a0.z += v0.z; a0.w += v0.w;
        a1.x += v1.x; a1.y += v1.y; a1.z += v1.z; a1.w += v1.w;
        a2.x += v2.x; a2.y += v2.y; a2.z += v2.z; a2.w += v2.w;
        a3.x += v3.x; a3.y += v3.y; a3.z += v3.z; a3.w += v3.w;
    }
    float sc = scale[i];
    const float4* lc = (const float4*)(local + (size_t)i * N_CLASS);
    float4* op = (float4*)(Lout + (size_t)i * N_CLASS);
    float4 l0 = lc[0], l1 = lc[1], l2 = lc[2], l3 = lc[3];
    float4 r0, r1, r2, r3;
    r0.x = sc*a0.x + ALPHA*l0.x; r0.y = sc*a0.y + ALPHA*l0.y;
    r0.z = sc*a0.z + ALPHA*l0.z; r0.w = sc*a0.w + ALPHA*l0.w;
    r1.x = sc*a1.x + ALPHA*l1.x; r1.y = sc*a1.y + ALPHA*l1.y;
    r1.z = sc*a1.z + ALPHA*l1.z; r1.w = sc*a1.w + ALPHA*l1.w;
    r2.x = sc*a2.x + ALPHA*l2.x; r2.y = sc*a2.y + ALPHA*l2.y;
    r2.z = sc*a2.z + ALPHA*l2.z; r2.w = sc*a2.w + ALPHA*l2.w;
    r3.x = sc*a3.x + ALPHA*l3.x; r3.y = sc*a3.y + ALPHA*l3.y;
    r3.z = sc*a3.z + ALPHA*l3.z; r3.w = sc*a3.w + ALPHA*l3.w;
    op[0] = r0; op[1] = r1; op[2] = r2; op[3] = r3;
}

// ---------------------------------------------------------------------------
// In-place log_softmax over C=16
// ---------------------------------------------------------------------------
__global__ void lsm_kernel(float* __restrict__ out) {
    int i = blockIdx.x * blockDim.x + threadIdx.x;
    if (i >= N_NODES) return;
    float4* p = (float4*)(out + (size_t)i * N_CLASS);
    float v[16];
    float4 t0 = p[0], t1 = p[1], t2 = p[2], t3 = p[3];
    v[0]=t0.x; v[1]=t0.y; v[2]=t0.z; v[3]=t0.w;
    v[4]=t1.x; v[5]=t1.y; v[6]=t1.z; v[7]=t1.w;
    v[8]=t2.x; v[9]=t2.y; v[10]=t2.z; v[11]=t2.w;
    v[12]=t3.x; v[13]=t3.y; v[14]=t3.z; v[15]=t3.w;
    float m = v[0];
#pragma unroll
    for (int k = 1; k < 16; ++k) m = fmaxf(m, v[k]);
    float sum = 0.f;
#pragma unroll
    for (int k = 0; k < 16; ++k) sum += expf(v[k] - m);
    float ls = logf(sum) + m;
#pragma unroll
    for (int k = 0; k < 16; ++k) v[k] -= ls;
    t0.x=v[0]; t0.y=v[1]; t0.z=v[2]; t0.w=v[3];
    t1.x=v[4]; t1.y=v[5]; t1.z=v[6]; t1.w=v[7];
    t2.x=v[8]; t2.y=v[9]; t2.z=v[10]; t2.w=v[11];
    t3.x=v[12]; t3.y=v[13]; t3.z=v[14]; t3.w=v[15];
    p[0]=t0; p[1]=t1; p[2]=t2; p[3]=t3;
}

// ---------------------------------------------------------------------------
extern "C" void kernel_launch(void* const* d_in, const int* in_sizes, int n_in,
                              void* d_out, int out_size, void* d_ws, size_t ws_size,
                              hipStream_t stream) {
    const float* x    = (const float*)d_in[0];
    const float* W1   = (const float*)d_in[1];
    const float* W2   = (const float*)d_in[2];
    const int*   esrc = (const int*)d_in[3];
    const int*   edst = (const int*)d_in[4];
    float* out = (float*)d_out;
    char*  ws  = (char*)d_ws;

    // workspace layout (bytes)
    float* local   = (float*)(ws + 0);           // 6,400,000
    float* P1      = (float*)(ws + 6400000);     // 6,400,000
    int*   deg     = (int*)  (ws + 12800000);    //   400,000
    int*   row_ptr = (int*)  (ws + 13200000);    //   400,004
    int*   cursor  = (int*)  (ws + 13600512);    //   400,000
    float* scale   = (float*)(ws + 14000512);    //   400,000
    int*   col     = (int*)  (ws + 14400512);    // 12,800,000  (end ~27.2 MB)

    hipMemsetAsync(deg, 0, N_NODES * sizeof(int), stream);

    fused_mlp<<<(N_NODES + BM - 1) / BM, 256, 0, stream>>>(x, W1, W2, local);

    hist_kernel<<<(N_EDGES + 255) / 256, 256, 0, stream>>>(esrc, deg);
    scan_kernel<<<1, 1024, 0, stream>>>(deg, row_ptr, cursor, scale);
    scatter_kernel<<<(N_EDGES + 255) / 256, 256, 0, stream>>>(esrc, edst, cursor, col);

    const int ngrid = (N_NODES + 255) / 256;
    spmm_kernel<<<ngrid, 256, 0, stream>>>(row_ptr, col, scale, local, local, P1);
    spmm_kernel<<<ngrid, 256, 0, stream>>>(row_ptr, col, scale, P1, local, out);
    lsm_kernel<<<ngrid, 256, 0, stream>>>(out);
}

// Round 2
// 1108.736 us; speedup vs baseline: 1.1523x; 1.1523x over previous
//
#include <hip/hip_runtime.h>
#include <math.h>

#define N_NODES 100000
#define N_FEAT  512
#define HIDDEN  128
#define N_CLASS 16
#define N_EDGES 3200000
#define ALPHA   0.25f

typedef __attribute__((ext_vector_type(8))) short short8;
typedef __attribute__((ext_vector_type(4))) float float4v;

__device__ inline short f2b(float f) {
    union { float f; unsigned u; } c; c.f = f;
    unsigned r = c.u + 0x7FFF + ((c.u >> 16) & 1);   // round-to-nearest-even
    return (short)(r >> 16);
}

// ---------------------------------------------------------------------------
// prep: W1t_bf[n=128][k=512] = bf16(W1[k][n]);  W2t_bf[n=16][k=128] = bf16(W2[k][n])
// ---------------------------------------------------------------------------
__global__ void prep_kernel(const float* __restrict__ W1, const float* __restrict__ W2,
                            short* __restrict__ W1t, short* __restrict__ W2t) {
    int t = blockIdx.x * 256 + threadIdx.x;
    if (t < N_FEAT * HIDDEN) {                 // t = n*512 + k
        int k = t & 511, n = t >> 9;
        W1t[t] = f2b(W1[(size_t)k * HIDDEN + n]);
    }
    int t2 = t - N_FEAT * HIDDEN;
    if (t2 >= 0 && t2 < HIDDEN * N_CLASS) {    // t2 = n*128 + k
        int k = t2 & 127, n = t2 >> 7;
        W2t[t2] = f2b(W2[(size_t)k * N_CLASS + n]);
    }
}

// ---------------------------------------------------------------------------
// Fused MLP via MFMA: local = relu(x@W1)@W2, bf16 inputs / fp32 accum
// Block: 256 thr (4 waves), 128-row x 128-col tile, 16x16x32 bf16 MFMA.
// ---------------------------------------------------------------------------
__global__ __launch_bounds__(256) void mlp_mfma(const float* __restrict__ x,
                                                const short* __restrict__ W1t,
                                                const short* __restrict__ W2t,
                                                float* __restrict__ local_out) {
    __shared__ __align__(16) short As[128 * 32];        // 8 KB  x-tile bf16
    __shared__ __align__(16) short Bts[128 * 32];       // 8 KB  W1t-tile bf16
    __shared__ __align__(16) short Hs[128 * 136];       // 34 KB hidden bf16 (pad 8)
    __shared__ __align__(16) short W2ts[16 * 136];      // 4.25 KB

    const int tid  = threadIdx.x;
    const int wave = tid >> 6;
    const int wl   = tid & 63;
    const int lane15 = wl & 15;
    const int quad   = wl >> 4;
    const long block_row = (long)blockIdx.x * 128;

    // stage W2t once (16x128 -> padded 136)
    {
        int n = tid >> 4, koff = (tid & 15) * 8;
        *(short8*)&W2ts[n * 136 + koff] = *(const short8*)&W2t[n * 128 + koff];
    }

    float4v acc[4][4];
#pragma unroll
    for (int i = 0; i < 4; ++i)
#pragma unroll
        for (int j = 0; j < 4; ++j) acc[i][j] = (float4v){0.f, 0.f, 0.f, 0.f};

    const int wr0 = (wave >> 1) * 64;   // wave row offset
    const int wc0 = (wave & 1) * 64;    // wave col offset

    for (int k0 = 0; k0 < N_FEAT; k0 += 32) {
        // ---- stage A: x[128 rows][k0..k0+32) fp32 -> bf16
#pragma unroll
        for (int l = 0; l < 2; ++l) {
            int c = tid + l * 256;          // 512 chunks of 8 floats
            int row = c >> 2, off = (c & 3) * 8;
            long grow = block_row + row;
            float4 v0 = make_float4(0.f, 0.f, 0.f, 0.f), v1 = v0;
            if (grow < N_NODES) {
                const float* p = x + grow * N_FEAT + k0 + off;
                v0 = *(const float4*)p;
                v1 = *(const float4*)(p + 4);
            }
            short8 h;
            h[0] = f2b(v0.x); h[1] = f2b(v0.y); h[2] = f2b(v0.z); h[3] = f2b(v0.w);
            h[4] = f2b(v1.x); h[5] = f2b(v1.y); h[6] = f2b(v1.z); h[7] = f2b(v1.w);
            *(short8*)&As[row * 32 + off] = h;
        }
        // ---- stage B: W1t[128 n][k0..k0+32) bf16 (already transposed)
#pragma unroll
        for (int l = 0; l < 2; ++l) {
            int c = tid + l * 256;
            int n = c >> 2, koff = (c & 3) * 8;
            *(short8*)&Bts[n * 32 + koff] = *(const short8*)&W1t[n * 512 + k0 + koff];
        }
        __syncthreads();

        short8 af[4], bfr[4];
#pragma unroll
        for (int i = 0; i < 4; ++i)
            af[i] = *(short8*)&As[(wr0 + i * 16 + lane15) * 32 + quad * 8];
#pragma unroll
        for (int j = 0; j < 4; ++j)
            bfr[j] = *(short8*)&Bts[(wc0 + j * 16 + lane15) * 32 + quad * 8];
#pragma unroll
        for (int i = 0; i < 4; ++i)
#pragma unroll
            for (int j = 0; j < 4; ++j)
                acc[i][j] = __builtin_amdgcn_mfma_f32_16x16x32_bf16(af[i], bfr[j], acc[i][j], 0, 0, 0);
        __syncthreads();
    }

    // ---- relu -> Hs (bf16).  C layout: col=lane&15, row=quad*4+reg
#pragma unroll
    for (int i = 0; i < 4; ++i)
#pragma unroll
        for (int j = 0; j < 4; ++j)
#pragma unroll
            for (int r = 0; r < 4; ++r) {
                int row = wr0 + i * 16 + quad * 4 + r;
                int colh = wc0 + j * 16 + lane15;
                Hs[row * 136 + colh] = f2b(fmaxf(acc[i][j][r], 0.f));
            }
    __syncthreads();

    // ---- GEMM2 via MFMA: (128x128 bf16) @ (128x16 bf16); wave handles 32 rows
    float4v acc2[2];
    acc2[0] = (float4v){0.f, 0.f, 0.f, 0.f};
    acc2[1] = acc2[0];
#pragma unroll
    for (int ks = 0; ks < 4; ++ks) {
        short8 a0 = *(short8*)&Hs[(wave * 32 + lane15) * 136 + ks * 32 + quad * 8];
        short8 a1 = *(short8*)&Hs[(wave * 32 + 16 + lane15) * 136 + ks * 32 + quad * 8];
        short8 b  = *(short8*)&W2ts[lane15 * 136 + ks * 32 + quad * 8];
        acc2[0] = __builtin_amdgcn_mfma_f32_16x16x32_bf16(a0, b, acc2[0], 0, 0, 0);
        acc2[1] = __builtin_amdgcn_mfma_f32_16x16x32_bf16(a1, b, acc2[1], 0, 0, 0);
    }
#pragma unroll
    for (int i2 = 0; i2 < 2; ++i2)
#pragma unroll
        for (int r = 0; r < 4; ++r) {
            long grow = block_row + wave * 32 + i2 * 16 + quad * 4 + r;
            if (grow < N_NODES)
                local_out[grow * N_CLASS + lane15] = acc2[i2][r];
        }
}

// ---------------------------------------------------------------------------
// CSR build
// ---------------------------------------------------------------------------
__global__ void hist_kernel(const int* __restrict__ src, int* __restrict__ deg) {
    int e = blockIdx.x * blockDim.x + threadIdx.x;
    if (e < N_EDGES) atomicAdd(&deg[src[e]], 1);
}

__global__ __launch_bounds__(1024) void scan_kernel(const int* __restrict__ deg,
                                                    int* __restrict__ row_ptr,
                                                    int* __restrict__ cursor,
                                                    float* __restrict__ scale) {
    __shared__ int sums[1024];
    const int tid = threadIdx.x;
    const int chunk = (N_NODES + 1023) / 1024;   // 98
    int start = tid * chunk;
    int end   = start + chunk; if (end > N_NODES) end = N_NODES;
    if (start > N_NODES) start = N_NODES;

    int s = 0;
    for (int i = start; i < end; ++i) s += deg[i];
    sums[tid] = s;
    __syncthreads();
    for (int off = 1; off < 1024; off <<= 1) {
        int t = (tid >= off) ? sums[tid - off] : 0;
        __syncthreads();
        sums[tid] += t;
        __syncthreads();
    }
    int run = sums[tid] - s;
    for (int i = start; i < end; ++i) {
        row_ptr[i] = run;
        cursor[i]  = run;
        int d = deg[i];
        scale[i] = (1.0f - ALPHA) / fmaxf((float)d, 1e-12f);
        run += d;
    }
    if (tid == 1023) row_ptr[N_NODES] = sums[1023];
}

__global__ void scatter_kernel(const int* __restrict__ src,
                               const int* __restrict__ dst,
                               int* __restrict__ cursor,
                               int* __restrict__ col) {
    int e = blockIdx.x * blockDim.x + threadIdx.x;
    if (e < N_EDGES) {
        int pos = atomicAdd(&cursor[src[e]], 1);
        col[pos] = dst[e];
    }
}

// ---------------------------------------------------------------------------
// SpMM: 16 lanes per node, coalesced 64B row gathers, optional fused log_softmax
// ---------------------------------------------------------------------------
template <bool LSM>
__global__ void spmm_kernel(const int* __restrict__ row_ptr,
                            const int* __restrict__ col,
                            const float* __restrict__ scale,
                            const float* __restrict__ Lin,
                            const float* __restrict__ local,
                            float* __restrict__ Lout) {
    int tid = blockIdx.x * 256 + threadIdx.x;
    int g = tid >> 4;          // node
    int lane = tid & 15;       // class
    if (g >= N_NODES) return;
    int wl = threadIdx.x & 63;
    int gbase = wl & 48;       // group base lane within wave

    int s = row_ptr[g], e = row_ptr[g + 1];
    float acc = 0.f;
    for (int base = s; base < e; base += 16) {
        int cv = (base + lane < e) ? col[base + lane] : 0;
        int m = e - base; if (m > 16) m = 16;
        for (int j = 0; j < m; ++j) {
            int c = __shfl(cv, gbase + j);
            acc += Lin[(size_t)c * N_CLASS + lane];
        }
    }
    float r = scale[g] * acc + ALPHA * local[(size_t)g * N_CLASS + lane];
    if (!LSM) {
        Lout[(size_t)g * N_CLASS + lane] = r;
    } else {
        float mx = r;
#pragma unroll
        for (int off = 8; off >= 1; off >>= 1) mx = fmaxf(mx, __shfl_xor(mx, off));
        float ex = expf(r - mx);
        float sm = ex;
#pragma unroll
        for (int off = 8; off >= 1; off >>= 1) sm += __shfl_xor(sm, off);
        Lout[(size_t)g * N_CLASS + lane] = r - mx - logf(sm);
    }
}

// ---------------------------------------------------------------------------
extern "C" void kernel_launch(void* const* d_in, const int* in_sizes, int n_in,
                              void* d_out, int out_size, void* d_ws, size_t ws_size,
                              hipStream_t stream) {
    const float* x    = (const float*)d_in[0];
    const float* W1   = (const float*)d_in[1];
    const float* W2   = (const float*)d_in[2];
    const int*   esrc = (const int*)d_in[3];
    const int*   edst = (const int*)d_in[4];
    float* out = (float*)d_out;
    char*  ws  = (char*)d_ws;

    // workspace layout (bytes)
    float* local   = (float*)(ws + 0);           // 6,400,000
    float* P1      = (float*)(ws + 6400000);     // 6,400,000 (ping)
    short* W1t     = (short*)(ws + 6400000);     // overlays P1: dead until spmm1
    short* W2t     = (short*)(ws + 6531072);     //   4,096
    int*   deg     = (int*)  (ws + 12800000);    //   400,000
    int*   row_ptr = (int*)  (ws + 13200000);    //   400,004
    int*   cursor  = (int*)  (ws + 13600512);    //   400,000
    float* scale   = (float*)(ws + 14000512);    //   400,000
    int*   col     = (int*)  (ws + 14400512);    // 12,800,000

    hipMemsetAsync(deg, 0, N_NODES * sizeof(int), stream);

    prep_kernel<<<(N_FEAT * HIDDEN + HIDDEN * N_CLASS + 255) / 256, 256, 0, stream>>>(W1, W2, W1t, W2t);
    mlp_mfma<<<(N_NODES + 127) / 128, 256, 0, stream>>>(x, W1t, W2t, local);

    hist_kernel<<<(N_EDGES + 255) / 256, 256, 0, stream>>>(esrc, deg);
    scan_kernel<<<1, 1024, 0, stream>>>(deg, row_ptr, cursor, scale);
    scatter_kernel<<<(N_EDGES + 255) / 256, 256, 0, stream>>>(esrc, edst, cursor, col);

    const int sgrid = (N_NODES * 16 + 255) / 256;
    spmm_kernel<false><<<sgrid, 256, 0, stream>>>(row_ptr, col, scale, local, local, P1);
    spmm_kernel<true ><<<sgrid, 256, 0, stream>>>(row_ptr, col, scale, P1, local, out);
}